// Round 1
// baseline (206.070 us; speedup 1.0000x reference)
//
#include <hip/hip_runtime.h>

#define NG 20000
#define NB 1024

constexpr int THREADS = 256;
constexpr int GPT = 2;                       // genes per thread
constexpr int GPB = THREADS * GPT;           // 512 genes per block
constexpr int NGB = (NG + GPB - 1) / GPB;    // 40 gene blocks
constexpr int BB  = 16;                      // batches per block
constexpr int NBB = NB / BB;                 // 64 batch blocks

// Each thread owns 2 consecutive genes; all per-gene MLP params live in
// registers (58 floats); thread loops over 16 batches streaming x->out.
// x and out are each touched exactly once (coalesced float2) -> pure
// HBM-streaming kernel, ~246 MB total.
__global__ __launch_bounds__(THREADS, 4)
void cgm_kernel(const float* __restrict__ x,
                const float* __restrict__ w1,
                const float* __restrict__ b1,
                const float* __restrict__ w2,
                const float* __restrict__ b2,
                const float* __restrict__ wg,
                const float* __restrict__ bg,
                float* __restrict__ out)
{
    const int gb = (int)blockIdx.x % NGB;    // gene-chunk index
    const int bb = (int)blockIdx.x / NGB;    // batch-chunk index
    const int g0 = gb * GPB + (int)threadIdx.x * GPT;
    if (g0 >= NG) return;                    // tail gene block (gb==39, tid>=16)

    // ---- load per-gene params into registers (once per block) ----
    float4 W1[2][2], B1[2][2], W2[2][2];     // [tech][gene_j]
    float  B2v[2][2];
    #pragma unroll
    for (int t = 0; t < 2; ++t) {
        #pragma unroll
        for (int j = 0; j < 2; ++j) {
            const size_t r = (size_t)t * NG + (size_t)(g0 + j);
            W1[t][j]  = *(const float4*)(w1 + r * 4);
            B1[t][j]  = *(const float4*)(b1 + r * 4);
            W2[t][j]  = *(const float4*)(w2 + r * 4);
            B2v[t][j] = b2[r];
        }
    }
    // wg is [G,2] row-major: wg[g0][0], wg[g0][1], wg[g0+1][0], wg[g0+1][1]
    const float4 wgv = *(const float4*)(wg + (size_t)g0 * 2);
    const float2 bgv = *(const float2*)(bg + g0);

    const int b_lo = bb * BB;
    #pragma unroll 4
    for (int bi = 0; bi < BB; ++bi) {
        const int b = b_lo + bi;
        const float* xb = x + (size_t)b * (2 * NG) + g0;
        const float2 x0 = *(const float2*)(xb);        // tech 0
        const float2 x1 = *(const float2*)(xb + NG);   // tech 1

        float s[2][2];                                 // [tech][gene_j]
        #pragma unroll
        for (int t = 0; t < 2; ++t) {
            const float2 xv = (t == 0) ? x0 : x1;
            #pragma unroll
            for (int j = 0; j < 2; ++j) {
                const float v = (j == 0) ? xv.x : xv.y;
                float h, acc = 0.f;
                h = fmaxf(fmaf(v, W1[t][j].x, B1[t][j].x), 0.f); acc = fmaf(h, W2[t][j].x, acc);
                h = fmaxf(fmaf(v, W1[t][j].y, B1[t][j].y), 0.f); acc = fmaf(h, W2[t][j].y, acc);
                h = fmaxf(fmaf(v, W1[t][j].z, B1[t][j].z), 0.f); acc = fmaf(h, W2[t][j].z, acc);
                h = fmaxf(fmaf(v, W1[t][j].w, B1[t][j].w), 0.f); acc = fmaf(h, W2[t][j].w, acc);
                s[t][j] = fmaxf(acc + B2v[t][j], 0.f);
            }
        }
        // out[b,g] = relu(s0*wg[g,0] + s1*wg[g,1] + bg[g])
        float2 o;
        o.x = fmaxf(fmaf(s[0][0], wgv.x, fmaf(s[1][0], wgv.y, bgv.x)), 0.f);
        o.y = fmaxf(fmaf(s[0][1], wgv.z, fmaf(s[1][1], wgv.w, bgv.y)), 0.f);
        *(float2*)(out + (size_t)b * NG + g0) = o;
    }
}

extern "C" void kernel_launch(void* const* d_in, const int* in_sizes, int n_in,
                              void* d_out, int out_size, void* d_ws, size_t ws_size,
                              hipStream_t stream) {
    const float* x  = (const float*)d_in[0];
    const float* w1 = (const float*)d_in[1];
    const float* b1 = (const float*)d_in[2];
    const float* w2 = (const float*)d_in[3];
    const float* b2 = (const float*)d_in[4];
    const float* wg = (const float*)d_in[5];
    const float* bg = (const float*)d_in[6];
    float* out = (float*)d_out;

    dim3 grid(NGB * NBB);   // 40 * 64 = 2560 blocks
    cgm_kernel<<<grid, THREADS, 0, stream>>>(x, w1, b1, w2, b2, wg, bg, out);
}

// Round 2
// 54.617 us; speedup vs baseline: 3.7730x; 3.7730x over previous
//
#include <hip/hip_runtime.h>

#define NG 20000
#define NB 1024

typedef float v4f __attribute__((ext_vector_type(4)));

constexpr int THREADS = 256;            // 4 waves
constexpr int GENES_PER_BLOCK = 512;    // 128 gene-lanes * 4 genes
constexpr int NGB = 40;                 // ceil(20000/512)
constexpr int BB  = 32;                 // batches per block
constexpr int NBB = NB / BB;            // 32
constexpr int GB_PER_XCD = NGB / 8;     // 5 gene-chunks per XCD

// Half-wave tech split: lanes 0-31 = tech0, lanes 32-63 = tech1, same genes.
// Each thread owns 4 genes of one tech; params in registers (~64 VGPR);
// loop over 32 batches with NT float4 load of x and NT float4 store of out.
__global__ __launch_bounds__(THREADS, 4)
void cgm_kernel(const float* __restrict__ x,
                const float* __restrict__ w1,
                const float* __restrict__ b1,
                const float* __restrict__ w2,
                const float* __restrict__ b2,
                const float* __restrict__ wg,
                const float* __restrict__ bg,
                float* __restrict__ out)
{
    // XCD-aware mapping (heuristic: hw round-robins blocks over 8 XCDs by id).
    // Each XCD owns 5 gene-chunks x 32 batch-chunks -> param set ~300KB/L2.
    const int bid = (int)blockIdx.x;          // 0..1279
    const int xcd = bid & 7;
    const int j   = bid >> 3;                 // 0..159
    const int gb  = xcd * GB_PER_XCD + (j / NBB);   // 0..39
    const int bb  = j % NBB;                  // 0..31

    const int lane = (int)threadIdx.x & 63;
    const int wv   = (int)threadIdx.x >> 6;
    const int t    = lane >> 5;               // tech 0/1 per half-wave
    const int gl   = wv * 32 + (lane & 31);   // gene-lane 0..127
    const int gbase = gb * GENES_PER_BLOCK + gl * 4;
    if (gbase >= NG) return;                  // tail (gb==39): partners stay paired

    // ---- per-thread params in registers (own tech only) ----
    v4f W1[4], B1[4], W2[4];
    float B2v[4];
    const size_t r0 = (size_t)t * NG + (size_t)gbase;
    #pragma unroll
    for (int g = 0; g < 4; ++g) {
        W1[g]  = *(const v4f*)(w1 + (r0 + g) * 4);
        B1[g]  = *(const v4f*)(b1 + (r0 + g) * 4);
        W2[g]  = *(const v4f*)(w2 + (r0 + g) * 4);
        B2v[g] = b2[r0 + g];
    }
    // wg rows [g][2]: need both tech columns for the combine (lanes<32 use it)
    const v4f wgA = *(const v4f*)(wg + (size_t)gbase * 2);      // g0t0 g0t1 g1t0 g1t1
    const v4f wgB = *(const v4f*)(wg + (size_t)gbase * 2 + 4);  // g2t0 g2t1 g3t0 g3t1
    const v4f bgv = *(const v4f*)(bg + gbase);

    const float* xbase = x + (size_t)t * NG + (size_t)gbase;
    float*       obase = out + (size_t)gbase;

    const int b_lo = bb * BB;
    #pragma unroll 4
    for (int bi = 0; bi < BB; ++bi) {
        const size_t b = (size_t)(b_lo + bi);
        const v4f xv = __builtin_nontemporal_load((const v4f*)(xbase + b * (2 * NG)));

        float s[4];
        #pragma unroll
        for (int g = 0; g < 4; ++g) {
            const float v = xv[g];
            float h, acc = 0.f;
            h = fmaxf(fmaf(v, W1[g].x, B1[g].x), 0.f); acc = fmaf(h, W2[g].x, acc);
            h = fmaxf(fmaf(v, W1[g].y, B1[g].y), 0.f); acc = fmaf(h, W2[g].y, acc);
            h = fmaxf(fmaf(v, W1[g].z, B1[g].z), 0.f); acc = fmaf(h, W2[g].z, acc);
            h = fmaxf(fmaf(v, W1[g].w, B1[g].w), 0.f); acc = fmaf(h, W2[g].w, acc);
            s[g] = fmaxf(acc + B2v[g], 0.f);
        }

        // exchange shrink outputs across the tech half-waves (partner = lane^32)
        float so[4];
        #pragma unroll
        for (int g = 0; g < 4; ++g) so[g] = __shfl_xor(s[g], 32, 64);

        if (t == 0) {   // lanes 0-31 hold (s=tech0, so=tech1): combine + store
            v4f o;
            o.x = fmaxf(fmaf(s[0], wgA.x, fmaf(so[0], wgA.y, bgv.x)), 0.f);
            o.y = fmaxf(fmaf(s[1], wgA.z, fmaf(so[1], wgA.w, bgv.y)), 0.f);
            o.z = fmaxf(fmaf(s[2], wgB.x, fmaf(so[2], wgB.y, bgv.z)), 0.f);
            o.w = fmaxf(fmaf(s[3], wgB.z, fmaf(so[3], wgB.w, bgv.w)), 0.f);
            __builtin_nontemporal_store(o, (v4f*)(obase + b * NG));
        }
    }
}

extern "C" void kernel_launch(void* const* d_in, const int* in_sizes, int n_in,
                              void* d_out, int out_size, void* d_ws, size_t ws_size,
                              hipStream_t stream) {
    const float* x  = (const float*)d_in[0];
    const float* w1 = (const float*)d_in[1];
    const float* b1 = (const float*)d_in[2];
    const float* w2 = (const float*)d_in[3];
    const float* b2 = (const float*)d_in[4];
    const float* wg = (const float*)d_in[5];
    const float* bg = (const float*)d_in[6];
    float* out = (float*)d_out;

    dim3 grid(NGB * NBB);   // 40 * 32 = 1280 blocks (5 per CU exactly)
    cgm_kernel<<<grid, THREADS, 0, stream>>>(x, w1, b1, w2, b2, wg, bg, out);
}